// Round 8
// baseline (214.931 us; speedup 1.0000x reference)
//
#include <hip/hip_runtime.h>
#include <stdint.h>

// ---------------------------------------------------------------------------
// MixingLayer: b=16, m=64, f=128, k=64, L2=16, LMAX=4. ALL I/O IS FP32.
// SEG = [0,1,1,1,2,2,2,2,2,3,3,3,3,3,3,3]
//
// Round-8:
//   * fused GEMM reads x directly (f32, one-time -> 64 VGPRs) and y via
//     contiguous DMA from pre-transposed yT[fy][m][c] (f32). G-gen in f32.
//   * Cpart stored bf16: 134 MB -> 67 MB HBM round-trip.
//   * reduce merged into finish.
//
// ws layout (bytes):
//   Wb    bf16 [128 n][65536 kk]     @ 0          (16,777,216)
//   yT    f32  [128 fy][1024 m][16c] @ 16777216   ( 8,388,608)
//   Cpart bf16 [128 sp][1024][128]   @ 25165824   (33,554,432)
//   wfT   f32  [2][64 k][4 l][128 f] @ 58720256   (   262,144)
// ---------------------------------------------------------------------------

#define AS1 __attribute__((address_space(1)))
#define AS3 __attribute__((address_space(3)))

typedef __bf16 bf16x8 __attribute__((ext_vector_type(8)));
typedef float f32x4 __attribute__((ext_vector_type(4)));

__device__ __forceinline__ uint16_t f2b(float f) {
  uint32_t u = __float_as_uint(f);
  u += 0x7fffu + ((u >> 16) & 1u);   // RNE
  return (uint16_t)(u >> 16);
}
__device__ __forceinline__ float b2f(uint16_t u) {
  return __uint_as_float((uint32_t)u << 16);
}

// ---------------------------------------------------------------------------
// K0: blocks [0,4096): Wb = bf16(wx0|wy0)
//     blocks [4096,4608): yT[fy][m][c] = y[m][fy][c]   (f32 transpose)
//     blocks [4608,4640): wfT[((side*64+k)*4+l)*128+f] = wf_side[(l*128+f)*64+k]
// ---------------------------------------------------------------------------
__global__ __launch_bounds__(256) void convert_all(
    const float* __restrict__ wx0, const float* __restrict__ wy0,
    const float* __restrict__ y,
    const float* __restrict__ wxf, const float* __restrict__ wyf,
    uint16_t* __restrict__ Wb, float* __restrict__ yT,
    float* __restrict__ wfT) {
  if (blockIdx.x < 4096) {
    size_t i = ((size_t)blockIdx.x * 256 + threadIdx.x) * 8;
    const float* s = (i < 4194304) ? (wx0 + i) : (wy0 + (i - 4194304));
    float4 v0 = *(const float4*)s;
    float4 v1 = *(const float4*)(s + 4);
    uint32_t o0 = (uint32_t)f2b(v0.x) | ((uint32_t)f2b(v0.y) << 16);
    uint32_t o1 = (uint32_t)f2b(v0.z) | ((uint32_t)f2b(v0.w) << 16);
    uint32_t o2 = (uint32_t)f2b(v1.x) | ((uint32_t)f2b(v1.y) << 16);
    uint32_t o3 = (uint32_t)f2b(v1.z) | ((uint32_t)f2b(v1.w) << 16);
    *(uint4*)(Wb + i) = make_uint4(o0, o1, o2, o3);
  } else if (blockIdx.x < 4608) {
    int g = (blockIdx.x - 4096) * 256 + threadIdx.x;  // 131072 = 1024 m x 128 fy
    int m = g >> 7, fy = g & 127;
    const float* src = y + (size_t)m * 2048 + fy * 16;   // contiguous per wave
    float* dst = yT + (size_t)fy * 16384 + m * 16;
#pragma unroll
    for (int ii = 0; ii < 4; ++ii)
      *(float4*)(dst + ii * 4) = *(const float4*)(src + ii * 4);
  } else {
    int base = (blockIdx.x - 4608) * 2048 + threadIdx.x * 8;
#pragma unroll
    for (int ii = 0; ii < 8; ++ii) {
      int idx = base + ii;
      int side = idx >> 15, rem = idx & 32767;
      int k = rem >> 9, l = (rem >> 7) & 3, f = rem & 127;
      const float* src = side ? wyf : wxf;
      wfT[idx] = src[((size_t)l * 128 + f) * 64 + k];
    }
  }
}

// ---------------------------------------------------------------------------
// K1: FUSED G-gen + split GEMM.
// grid (128 groups, 8 M-tiles); group g: fb = g>>3 (8 fx), fyg = g&7 (16 fy).
// 16 steps, step t: fy = fyg*16 + t; BK=32 kk = fy*512 + fb*32 + [0,32).
// linear%8 = fyg -> all 128 blocks of one fyg share an XCD (yT slab + x L2-hot).
// x[m, 4fx, 16c] f32 in 64 VGPRs (one-time). y per step: contiguous DMA from
// yT into yS chunks (m,pos), pos = cq ^ ((m>>1)&3) -> consumer 2-way (free).
// ---------------------------------------------------------------------------
__device__ __forceinline__ void gload_lds16(const void* g, void* l) {
  __builtin_amdgcn_global_load_lds((const AS1 uint32_t*)g, (AS3 uint32_t*)l, 16, 0, 0);
}

__global__ __launch_bounds__(256, 3) void fused_gemm(
    const float* __restrict__ x, const float* __restrict__ yT,
    const uint16_t* __restrict__ Wb, uint16_t* __restrict__ Cpart) {
  __shared__ __align__(16) uint16_t sA[2][128 * 40];  // padded stride 40
  __shared__ __align__(16) uint16_t sB[2][128 * 32];  // XOR-swizzled cols
  __shared__ __align__(16) float yS[2][2048];         // chunk g=(m*4+pos): 4 floats
  const int seg[16] = {0,1,1,1,2,2,2,2,2,3,3,3,3,3,3,3};

  int tid = threadIdx.x;
  int w = tid >> 6, lane = tid & 63;
  int g_id = blockIdx.x;
  int fb = g_id >> 3, fyg = g_id & 7;
  int FB = fb * 8;
  int fy0 = fyg * 16;
  int m0 = blockIdx.y * 128;
  int r = lane & 15, q = lane >> 4;
  int wm = w >> 1, wn = w & 1;
  int rowl = lane >> 2, qq = lane & 3;
  int m_loc = tid & 127, half = tid >> 7;

  // one-time: x[m_loc, FB+half*4+fxp, 0:16] f32 -> 64 VGPRs
  float xf[4][16];
  {
    const float* xp0 = x + (size_t)(m0 + m_loc) * 2048 + (FB + half * 4) * 16;
#pragma unroll
    for (int fxp = 0; fxp < 4; ++fxp)
#pragma unroll
      for (int cc = 0; cc < 4; ++cc) {
        float4 v = *(const float4*)(xp0 + fxp * 16 + cc * 4);
        xf[fxp][cc * 4 + 0] = v.x; xf[fxp][cc * 4 + 1] = v.y;
        xf[fxp][cc * 4 + 2] = v.z; xf[fxp][cc * 4 + 3] = v.w;
      }
  }

  f32x4 zero = {0.f, 0.f, 0.f, 0.f};
  f32x4 acc[4][4];
#pragma unroll
  for (int i = 0; i < 4; ++i)
#pragma unroll
    for (int j = 0; j < 4; ++j) acc[i][j] = zero;

  int bcol = qq ^ ((rowl >> 1) & 3);  // swizzled source col for B DMA

  // y DMA: 8 issues of 64 lanes x 16B per buffer; this wave does j=0,1.
  // chunk index g = (w*2+j)*64 + lane; m = g>>2, pos = g&3, cq = pos^((m>>1)&3)
  int yg0 = w * 128 + lane;          // j=0 chunk
  int ym0_ = yg0 >> 2, yp0 = yg0 & 3;
  int ycq0 = yp0 ^ ((ym0_ >> 1) & 3);
  int yg1 = yg0 + 64;                // j=1 chunk
  int ym1_ = yg1 >> 2, yp1 = yg1 & 3;
  int ycq1 = yp1 ^ ((ym1_ >> 1) & 3);
  const float* ysrc0 = yT + (size_t)(m0 + ym0_) * 16 + ycq0 * 4;
  const float* ysrc1 = yT + (size_t)(m0 + ym1_) * 16 + ycq1 * 4;

  auto issueB = [&](uint16_t* dstB, int t) {
    int kk0 = (fy0 + t) * 512 + FB * 4;
#pragma unroll
    for (int jj = 0; jj < 2; ++jj) {
      int blk = w * 2 + jj;  // wave-uniform
      int rowi = blk * 16 + rowl;
      gload_lds16(Wb + (size_t)rowi * 65536 + kk0 + bcol * 8, dstB + blk * 512);
    }
  };
  auto issueY = [&](float* dstY, int t) {
    size_t fyoff = (size_t)(fy0 + t) * 16384;
    gload_lds16(ysrc0 + fyoff, dstY + w * 512);        // j=0: chunks w*128..
    gload_lds16(ysrc1 + fyoff, dstY + w * 512 + 256);  // j=1
  };
  auto computeG = [&](const float* srcY, float* gg) {
    float yv[16];
#pragma unroll
    for (int cq = 0; cq < 4; ++cq) {
      int pos = cq ^ ((m_loc >> 1) & 3);
      float4 v = *(const float4*)&srcY[(m_loc * 4 + pos) * 4];
      yv[cq * 4 + 0] = v.x; yv[cq * 4 + 1] = v.y;
      yv[cq * 4 + 2] = v.z; yv[cq * 4 + 3] = v.w;
    }
#pragma unroll
    for (int p = 0; p < 16; ++p) gg[p] = 0.f;
#pragma unroll
    for (int fxp = 0; fxp < 4; ++fxp)
#pragma unroll
      for (int c = 0; c < 16; ++c)
        gg[fxp * 4 + seg[c]] += yv[c] * xf[fxp][c];
  };
  auto writeA = [&](uint16_t* dstA, const float* gg) {
    uint32_t o[8];
#pragma unroll
    for (int p = 0; p < 8; ++p)
      o[p] = (uint32_t)f2b(gg[2 * p]) | ((uint32_t)f2b(gg[2 * p + 1]) << 16);
    uint16_t* dst = dstA + m_loc * 40 + half * 16;
    *(uint4*)dst       = make_uint4(o[0], o[1], o[2], o[3]);
    *(uint4*)(dst + 8) = make_uint4(o[4], o[5], o[6], o[7]);
  };

  uint16_t *pAc = sA[0], *pAn = sA[1];
  uint16_t *pBc = sB[0], *pBn = sB[1];
  float *pYc = yS[0], *pYn = yS[1];

  float gg[16];
  // prologue
  issueY(pYc, 0);
  __syncthreads();                 // y(0) landed
  computeG(pYc, gg);
  writeA(pAc, gg);
  issueB(pBc, 0);
  issueY(pYn, 1);
  __syncthreads();                 // sA[0]/sB[0]/y(1) ready

  for (int t = 0; t < 16; ++t) {
    if (t < 15) {
      issueB(pBn, t + 1);
      if (t < 14) issueY(pYc, t + 2);   // overwrites y(t) slot (consumed)
      computeG(pYn, gg);                // y(t+1), resident since last barrier
      writeA(pAn, gg);
    }
    bf16x8 a[4], b[4];
#pragma unroll
    for (int i = 0; i < 4; ++i)
      a[i] = *(const bf16x8*)&pAc[(wm * 64 + i * 16 + r) * 40 + q * 8];
#pragma unroll
    for (int j = 0; j < 4; ++j) {
      int row = wn * 64 + j * 16 + r;
      int pos = q ^ ((row >> 1) & 3);   // un-swizzle
      b[j] = *(const bf16x8*)&pBc[row * 32 + pos * 8];
    }
#pragma unroll
    for (int i = 0; i < 4; ++i)
#pragma unroll
      for (int j = 0; j < 4; ++j)
        acc[i][j] = __builtin_amdgcn_mfma_f32_16x16x32_bf16(a[i], b[j], acc[i][j], 0, 0, 0);
    __syncthreads();                    // one barrier per step
    uint16_t* tp;
    tp = pAc; pAc = pAn; pAn = tp;
    tp = pBc; pBc = pBn; pBn = tp;
    float* fp2;
    fp2 = pYc; pYc = pYn; pYn = fp2;
  }

  // epilogue: Cpart bf16. C/D layout: col(n)=lane&15, row(m)=(lane>>4)*4+reg
  uint16_t* cbase = Cpart + (size_t)g_id * 131072;  // 1024*128 per partial
#pragma unroll
  for (int i = 0; i < 4; ++i)
#pragma unroll
    for (int j = 0; j < 4; ++j)
#pragma unroll
      for (int reg = 0; reg < 4; ++reg) {
        int mm = m0 + wm * 64 + i * 16 + q * 4 + reg;
        int nn = wn * 64 + j * 16 + r;
        cbase[(size_t)mm * 128 + nn] = f2b(acc[i][j][reg]);
      }
}

// ---------------------------------------------------------------------------
// K2: ONE BLOCK PER bm: reduce 128 bf16 partials, 2 MLP stages
// (bias[st][m][j], m=bm&63), gates via wfT, fused elementwise output.
// ---------------------------------------------------------------------------
__global__ __launch_bounds__(256) void finish_kernel(
    const float* __restrict__ x, const float* __restrict__ y,
    const float* __restrict__ wx_mlp, const float* __restrict__ bx_mlp,
    const float* __restrict__ wy_mlp, const float* __restrict__ by_mlp,
    const float* __restrict__ wfT,
    const uint16_t* __restrict__ Cpart, float* __restrict__ out) {
  const int seg[16] = {0,1,1,1,2,2,2,2,2,3,3,3,3,3,3,3};
  __shared__ float sred[256];
  __shared__ float sm[128];
  __shared__ float sg[2][128][4];
  int t = threadIdx.x;
  int bm = blockIdx.x;
  int mi = bm & 63;

  {  // split-K reduce: 256 threads, each sums 64 of the 128 bf16 partials
    int col = t & 127, hh = t >> 7;
    float s = 0.f;
#pragma unroll 8
    for (int sp = hh * 64; sp < hh * 64 + 64; ++sp)
      s += b2f(Cpart[(size_t)sp * 131072 + (size_t)bm * 128 + col]);
    sred[t] = s;
  }
  __syncthreads();
  if (t < 128) sm[t] = sred[t] + sred[t + 128];  // [0:64)=mx, [64:128)=my
  __syncthreads();

  for (int st = 0; st < 2; ++st) {
    float v = 0.f;
    if (t < 128) {
      int side = t >> 6, j = t & 63;
      const float* wmlp = side ? wy_mlp : wx_mlp;
      const float* bmlp = side ? by_mlp : bx_mlp;
      const float* mv = sm + side * 64;
#pragma unroll 8
      for (int k = 0; k < 64; ++k)
        v += mv[k] * wmlp[(st * 64 + k) * 64 + j];
      v += bmlp[(st * 64 + mi) * 64 + j];
      v = v / (1.f + __expf(-v));
    }
    __syncthreads();
    if (t < 128) sm[t] = v;
    __syncthreads();
  }

  {  // gates: side wave-uniform, coalesced wfT reads
    int side = t >> 7, f = t & 127;
    const float* base = wfT + side * 32768;  // [k][l][f]
    const float* mv = sm + side * 64;
    float gg[4] = {0.f, 0.f, 0.f, 0.f};
#pragma unroll 8
    for (int k = 0; k < 64; ++k) {
      float m2 = mv[k];
#pragma unroll
      for (int l = 0; l < 4; ++l)
        gg[l] += m2 * base[(k * 4 + l) * 128 + f];
    }
#pragma unroll
    for (int l = 0; l < 4; ++l)
      sg[side][f][l] = gg[l] / (1.f + __expf(-gg[l]));
  }
  __syncthreads();

  {  // output: thread -> (f, half), 8 floats; fully coalesced
    int f = t >> 1, half = t & 1;
    size_t base = ((size_t)bm * 128 + f) * 16 + half * 8;
    float4 xa = *(const float4*)(x + base), xb4 = *(const float4*)(x + base + 4);
    float4 ya = *(const float4*)(y + base), yb4 = *(const float4*)(y + base + 4);
    float xv[8] = {xa.x, xa.y, xa.z, xa.w, xb4.x, xb4.y, xb4.z, xb4.w};
    float yv[8] = {ya.x, ya.y, ya.z, ya.w, yb4.x, yb4.y, yb4.z, yb4.w};
    float o[8];
#pragma unroll
    for (int ii = 0; ii < 8; ++ii) {
      int c = half * 8 + ii;
      o[ii] = sg[0][f][seg[c]] * xv[ii] + sg[1][f][seg[c]] * yv[ii];
    }
    *(float4*)(out + base)     = make_float4(o[0], o[1], o[2], o[3]);
    *(float4*)(out + base + 4) = make_float4(o[4], o[5], o[6], o[7]);
  }
}

// ---------------------------------------------------------------------------
extern "C" void kernel_launch(void* const* d_in, const int* in_sizes, int n_in,
                              void* d_out, int out_size, void* d_ws, size_t ws_size,
                              hipStream_t stream) {
  const float* x      = (const float*)d_in[0];
  const float* y      = (const float*)d_in[1];
  const float* wx0    = (const float*)d_in[2];
  const float* wy0    = (const float*)d_in[3];
  const float* wx_mlp = (const float*)d_in[4];
  const float* bx_mlp = (const float*)d_in[5];
  const float* wy_mlp = (const float*)d_in[6];
  const float* by_mlp = (const float*)d_in[7];
  const float* wxf    = (const float*)d_in[8];
  const float* wyf    = (const float*)d_in[9];
  float* out = (float*)d_out;

  uint16_t* Wb    = (uint16_t*)d_ws;                               // 16,777,216 B
  float*    yT    = (float*)((char*)d_ws + (size_t)16777216);      //  8,388,608 B
  uint16_t* Cpart = (uint16_t*)((char*)d_ws + (size_t)25165824);   // 33,554,432 B
  float*    wfT   = (float*)((char*)d_ws + (size_t)58720256);      //    262,144 B

  convert_all<<<4640, 256, 0, stream>>>(wx0, wy0, y, wxf, wyf, Wb, yT, wfT);
  fused_gemm<<<dim3(128, 8), 256, 0, stream>>>(x, yT, Wb, Cpart);
  finish_kernel<<<1024, 256, 0, stream>>>(x, y, wx_mlp, bx_mlp, wy_mlp, by_mlp,
                                          wfT, Cpart, out);
}

// Round 10
// 194.247 us; speedup vs baseline: 1.1065x; 1.1065x over previous
//
#include <hip/hip_runtime.h>
#include <stdint.h>

// ---------------------------------------------------------------------------
// MixingLayer: b=16, m=64, f=128, k=64, L2=16, LMAX=4. ALL I/O IS FP32.
// SEG = [0,1,1,1,2,2,2,2,2,3,3,3,3,3,3,3]
//
// Round-10 = round-9 (register-staged fused GEMM, AITER-style) with the
// compile fix: no `static __shared__`, no LDS pointer-array initializers
// (integer offsets instead).
//   * No convert kernel: W/x/y read f32 straight from inputs, converted
//     inline to bf16. G recomputed per step from register-resident x.
//   * Global->VGPR prefetch issued 1-2 steps ahead; LDS written from regs;
//     inter-step barrier is raw "s_waitcnt lgkmcnt(0); s_barrier" so global
//     prefetches stay in flight across it (no vmcnt(0) drain per step).
//   * sA and sB both padded stride-40; no swizzle.
//   * Epilogue: C tile through LDS -> fully-coalesced bf16 Cpart stores.
//
// ws layout (bytes):
//   Cpart bf16 [128 sp][1024 bm][128 n] @ 0          (33,554,432)
//   wfT   f32  [2][64 k][4 l][128 f]    @ 33554432   (   262,144)
// ---------------------------------------------------------------------------

typedef __bf16 bf16x8 __attribute__((ext_vector_type(8)));
typedef float f32x4 __attribute__((ext_vector_type(4)));

__device__ __forceinline__ uint16_t f2b(float f) {
  uint32_t u = __float_as_uint(f);
  u += 0x7fffu + ((u >> 16) & 1u);   // RNE
  return (uint16_t)(u >> 16);
}
__device__ __forceinline__ float b2f(uint16_t u) {
  return __uint_as_float((uint32_t)u << 16);
}
__device__ __forceinline__ uint32_t pk2(float a, float b) {
  return (uint32_t)f2b(a) | ((uint32_t)f2b(b) << 16);
}

#if __has_builtin(__builtin_amdgcn_fdot2_f32_bf16)
typedef __bf16 bf16x2 __attribute__((ext_vector_type(2)));
__device__ __forceinline__ float dot2b(uint32_t a, uint32_t b, float c) {
  union { uint32_t u; bf16x2 v; } ua, ub;
  ua.u = a; ub.u = b;
  return __builtin_amdgcn_fdot2_f32_bf16(ua.v, ub.v, c, false);
}
#else
__device__ __forceinline__ float dot2b(uint32_t a, uint32_t b, float c) {
  float a0 = __uint_as_float(a << 16), a1 = __uint_as_float(a & 0xffff0000u);
  float b0 = __uint_as_float(b << 16), b1 = __uint_as_float(b & 0xffff0000u);
  return c + a0 * b0 + a1 * b1;
}
#endif

// LDS-only barrier: global prefetch loads stay outstanding (vmcnt untouched).
#define LGKM_BAR() asm volatile("s_waitcnt lgkmcnt(0)\n\ts_barrier" ::: "memory")

// ---------------------------------------------------------------------------
// K0: wfT[((side*64+k)*4+l)*128+f] = wf_side[(l*128+f)*64+k]  (256 KB, tiny)
// ---------------------------------------------------------------------------
__global__ __launch_bounds__(256) void wft_kernel(const float* __restrict__ wxf,
                                                  const float* __restrict__ wyf,
                                                  float* __restrict__ wfT) {
  int idx = blockIdx.x * 256 + threadIdx.x;   // 65536 total
  int side = idx >> 15;
  int rem = idx & 32767;
  int k = rem >> 9;
  int l = (rem >> 7) & 3;
  int f = rem & 127;
  const float* src = side ? wyf : wxf;
  wfT[idx] = src[((size_t)l * 128 + f) * 64 + k];
}

// ---------------------------------------------------------------------------
// K1: FUSED G-gen + split GEMM, register-staged.
// grid (128, 8): blockIdx.x = g_id -> fb = g>>3 (8 fx), fyg = g&7 (16 fy);
// blockIdx.y = M-tile. 16 steps, step t: fy = fyg*16+t, BK = 32 kk.
// Same-g_id mtile-siblings share an XCD (linear%8 = g_id%8) -> W slab L2-hot.
// ---------------------------------------------------------------------------
__global__ __launch_bounds__(256, 3) void fused_gemm(
    const float* __restrict__ x, const float* __restrict__ y,
    const float* __restrict__ wx0, const float* __restrict__ wy0,
    uint16_t* __restrict__ Cpart) {
  // 4 buffers of 128*40 bf16 (10240 B each): A0 A1 B0 B1 = 40960 B total.
  __shared__ __align__(16) uint16_t smem[20480];
  const int seg[16] = {0,1,1,1,2,2,2,2,2,3,3,3,3,3,3,3};
  const int aoff0 = 0, aoff1 = 5120, boff0 = 10240, boff1 = 15360;

  int tid = threadIdx.x;
  int w = tid >> 6, lane = tid & 63;
  int g_id = blockIdx.x;
  int fb = g_id >> 3, fyg = g_id & 7;
  int FB = fb * 8;
  int fy0 = fyg * 16;
  int m0 = blockIdx.y * 128;
  int r = lane & 15, q = lane >> 4;
  int wm = w >> 1, wn = w & 1;
  int m_loc = tid & 127, half = tid >> 7;
  int n_row = tid >> 1, kc = tid & 1;   // B staging role

  const float* xrow = x + (size_t)(m0 + m_loc) * 2048 + (FB + half * 4) * 16;
  const float* yrow = y + (size_t)(m0 + m_loc) * 2048;
  const float* wrow = (n_row < 64) ? (wx0 + (size_t)n_row * 65536)
                                   : (wy0 + (size_t)(n_row - 64) * 65536);
  const float* wbase = wrow + FB * 4 + kc * 16;

  // ---- prefetch registers (live across the lgkm-only barrier)
  float4 Bv[4], Yv[4];
  auto issue = [&](int t) {
    const float* bp = wbase + (size_t)(fy0 + t) * 512;
    Bv[0] = *(const float4*)(bp);
    Bv[1] = *(const float4*)(bp + 4);
    Bv[2] = *(const float4*)(bp + 8);
    Bv[3] = *(const float4*)(bp + 12);
    const float* ypt = yrow + (size_t)(fy0 + t) * 16;
    Yv[0] = *(const float4*)(ypt);
    Yv[1] = *(const float4*)(ypt + 4);
    Yv[2] = *(const float4*)(ypt + 8);
    Yv[3] = *(const float4*)(ypt + 12);
  };

  // ---- one-time x load + pack to bf16 (issue(0) first for overlap)
  float4 xv[16];
#pragma unroll
  for (int p = 0; p < 16; ++p) xv[p] = *(const float4*)(xrow + p * 4);
  issue(0);
  uint32_t xr[32];
#pragma unroll
  for (int fxp = 0; fxp < 4; ++fxp)
#pragma unroll
    for (int cc = 0; cc < 4; ++cc) {
      float4 v = xv[fxp * 4 + cc];
      xr[fxp * 8 + cc * 2 + 0] = pk2(v.x, v.y);
      xr[fxp * 8 + cc * 2 + 1] = pk2(v.z, v.w);
    }

  f32x4 zero = {0.f, 0.f, 0.f, 0.f};
  f32x4 acc[4][4];
#pragma unroll
  for (int i = 0; i < 4; ++i)
#pragma unroll
    for (int j = 0; j < 4; ++j) acc[i][j] = zero;

  auto stage = [&](int ao, int bo) {
    // --- B: convert prefetched W f32 -> bf16, write LDS (row n, pad 40)
    uint32_t bq[8];
#pragma unroll
    for (int p = 0; p < 4; ++p) {
      bq[2 * p]     = pk2(Bv[p].x, Bv[p].y);
      bq[2 * p + 1] = pk2(Bv[p].z, Bv[p].w);
    }
    uint16_t* bd = &smem[bo + n_row * 40 + kc * 16];
    *(uint4*)bd       = make_uint4(bq[0], bq[1], bq[2], bq[3]);
    *(uint4*)(bd + 8) = make_uint4(bq[4], bq[5], bq[6], bq[7]);
    // --- A: G-gen from register x and prefetched y
    uint32_t yq[8];
    yq[0] = pk2(Yv[0].x, Yv[0].y); yq[1] = pk2(Yv[0].z, Yv[0].w);
    yq[2] = pk2(Yv[1].x, Yv[1].y); yq[3] = pk2(Yv[1].z, Yv[1].w);
    yq[4] = pk2(Yv[2].x, Yv[2].y); yq[5] = pk2(Yv[2].z, Yv[2].w);
    yq[6] = pk2(Yv[3].x, Yv[3].y); yq[7] = pk2(Yv[3].z, Yv[3].w);
    uint32_t yl0 = yq[0] & 0xffffu, yh0 = yq[0] & 0xffff0000u;
    uint32_t yl4 = yq[4] & 0xffffu, yh4 = yq[4] & 0xffff0000u;
    float gg[16];
#pragma unroll
    for (int fxp = 0; fxp < 4; ++fxp) {
      const uint32_t* xp = xr + fxp * 8;
      gg[fxp * 4 + 0] = dot2b(xp[0], yl0, 0.f);
      gg[fxp * 4 + 1] = dot2b(xp[1], yq[1], dot2b(xp[0], yh0, 0.f));
      gg[fxp * 4 + 2] = dot2b(xp[4], yl4,
                          dot2b(xp[3], yq[3], dot2b(xp[2], yq[2], 0.f)));
      gg[fxp * 4 + 3] = dot2b(xp[7], yq[7], dot2b(xp[6], yq[6],
                          dot2b(xp[5], yq[5], dot2b(xp[4], yh4, 0.f))));
    }
    uint32_t go[8];
#pragma unroll
    for (int p = 0; p < 8; ++p) go[p] = pk2(gg[2 * p], gg[2 * p + 1]);
    uint16_t* ad = &smem[ao + m_loc * 40 + half * 16];
    *(uint4*)ad       = make_uint4(go[0], go[1], go[2], go[3]);
    *(uint4*)(ad + 8) = make_uint4(go[4], go[5], go[6], go[7]);
  };

  // prologue: stage step 0 into buf0, issue step 1, full barrier once
  stage(aoff0, boff0);
  issue(1);
  __syncthreads();

  for (int t = 0; t < 16; ++t) {
    int cur = t & 1;
    int aoc = cur ? aoff1 : aoff0, bocur = cur ? boff1 : boff0;
    int aon = cur ? aoff0 : aoff1, bonxt = cur ? boff0 : boff1;
    if (t < 15) stage(aon, bonxt);   // consumes issue(t+1)
    if (t < 14) issue(t + 2);        // stays in flight across barrier
    bf16x8 a[4], b[4];
#pragma unroll
    for (int i = 0; i < 4; ++i)
      a[i] = *(const bf16x8*)&smem[aoc + (wm * 64 + i * 16 + r) * 40 + q * 8];
#pragma unroll
    for (int j = 0; j < 4; ++j)
      b[j] = *(const bf16x8*)&smem[bocur + (wn * 64 + j * 16 + r) * 40 + q * 8];
#pragma unroll
    for (int i = 0; i < 4; ++i)
#pragma unroll
      for (int j = 0; j < 4; ++j)
        acc[i][j] = __builtin_amdgcn_mfma_f32_16x16x32_bf16(a[i], b[j], acc[i][j], 0, 0, 0);
    LGKM_BAR();   // LDS-only sync: no vmcnt(0) drain
  }

  // ---- epilogue: C tile -> LDS (bf16) -> fully coalesced global stores
  __syncthreads();   // full barrier before repurposing smem
#pragma unroll
  for (int i = 0; i < 4; ++i)
#pragma unroll
    for (int j = 0; j < 4; ++j)
#pragma unroll
      for (int reg = 0; reg < 4; ++reg) {
        int mm = wm * 64 + i * 16 + q * 4 + reg;
        int nn = wn * 64 + j * 16 + r;
        smem[mm * 128 + nn] = f2b(acc[i][j][reg]);  // 128x128 bf16 = 32 KB
      }
  __syncthreads();
  {
    int row = tid >> 1, ch = tid & 1;
    const uint16_t* csrc = &smem[row * 128 + ch * 64];
    uint16_t* cdst = Cpart + (size_t)g_id * 131072 +
                     (size_t)(m0 + row) * 128 + ch * 64;
#pragma unroll
    for (int kkk = 0; kkk < 8; ++kkk)
      *(uint4*)(cdst + kkk * 8) = *(const uint4*)(csrc + kkk * 8);
  }
}

// ---------------------------------------------------------------------------
// K2: ONE BLOCK PER bm: reduce 128 bf16 partials, 2 MLP stages
// (bias[st][m][j], m=bm&63), gates via wfT, fused elementwise output.
// ---------------------------------------------------------------------------
__global__ __launch_bounds__(256) void finish_kernel(
    const float* __restrict__ x, const float* __restrict__ y,
    const float* __restrict__ wx_mlp, const float* __restrict__ bx_mlp,
    const float* __restrict__ wy_mlp, const float* __restrict__ by_mlp,
    const float* __restrict__ wfT,
    const uint16_t* __restrict__ Cpart, float* __restrict__ out) {
  const int seg[16] = {0,1,1,1,2,2,2,2,2,3,3,3,3,3,3,3};
  __shared__ float sred[256];
  __shared__ float sm[128];
  __shared__ float sg[2][128][4];
  int t = threadIdx.x;
  int bm = blockIdx.x;
  int mi = bm & 63;

  {  // split-K reduce: 256 threads, each sums 64 of the 128 bf16 partials
    int col = t & 127, hh = t >> 7;
    float s = 0.f;
#pragma unroll 8
    for (int sp = hh * 64; sp < hh * 64 + 64; ++sp)
      s += b2f(Cpart[(size_t)sp * 131072 + (size_t)bm * 128 + col]);
    sred[t] = s;
  }
  __syncthreads();
  if (t < 128) sm[t] = sred[t] + sred[t + 128];  // [0:64)=mx, [64:128)=my
  __syncthreads();

  for (int st = 0; st < 2; ++st) {
    float v = 0.f;
    if (t < 128) {
      int side = t >> 6, j = t & 63;
      const float* wmlp = side ? wy_mlp : wx_mlp;
      const float* bmlp = side ? by_mlp : bx_mlp;
      const float* mv = sm + side * 64;
#pragma unroll 8
      for (int k = 0; k < 64; ++k)
        v += mv[k] * wmlp[(st * 64 + k) * 64 + j];
      v += bmlp[(st * 64 + mi) * 64 + j];
      v = v / (1.f + __expf(-v));
    }
    __syncthreads();
    if (t < 128) sm[t] = v;
    __syncthreads();
  }

  {  // gates: side wave-uniform, coalesced wfT reads
    int side = t >> 7, f = t & 127;
    const float* base = wfT + side * 32768;  // [k][l][f]
    const float* mv = sm + side * 64;
    float gg[4] = {0.f, 0.f, 0.f, 0.f};
#pragma unroll 8
    for (int k = 0; k < 64; ++k) {
      float m2 = mv[k];
#pragma unroll
      for (int l = 0; l < 4; ++l)
        gg[l] += m2 * base[(k * 4 + l) * 128 + f];
    }
#pragma unroll
    for (int l = 0; l < 4; ++l)
      sg[side][f][l] = gg[l] / (1.f + __expf(-gg[l]));
  }
  __syncthreads();

  {  // output: thread -> (f, half), 8 floats; fully coalesced
    int f = t >> 1, half = t & 1;
    size_t base = ((size_t)bm * 128 + f) * 16 + half * 8;
    float4 xa = *(const float4*)(x + base), xb4 = *(const float4*)(x + base + 4);
    float4 ya = *(const float4*)(y + base), yb4 = *(const float4*)(y + base + 4);
    float xv[8] = {xa.x, xa.y, xa.z, xa.w, xb4.x, xb4.y, xb4.z, xb4.w};
    float yv[8] = {ya.x, ya.y, ya.z, ya.w, yb4.x, yb4.y, yb4.z, yb4.w};
    float o[8];
#pragma unroll
    for (int ii = 0; ii < 8; ++ii) {
      int c = half * 8 + ii;
      o[ii] = sg[0][f][seg[c]] * xv[ii] + sg[1][f][seg[c]] * yv[ii];
    }
    *(float4*)(out + base)     = make_float4(o[0], o[1], o[2], o[3]);
    *(float4*)(out + base + 4) = make_float4(o[4], o[5], o[6], o[7]);
  }
}

// ---------------------------------------------------------------------------
extern "C" void kernel_launch(void* const* d_in, const int* in_sizes, int n_in,
                              void* d_out, int out_size, void* d_ws, size_t ws_size,
                              hipStream_t stream) {
  const float* x      = (const float*)d_in[0];
  const float* y      = (const float*)d_in[1];
  const float* wx0    = (const float*)d_in[2];
  const float* wy0    = (const float*)d_in[3];
  const float* wx_mlp = (const float*)d_in[4];
  const float* bx_mlp = (const float*)d_in[5];
  const float* wy_mlp = (const float*)d_in[6];
  const float* by_mlp = (const float*)d_in[7];
  const float* wxf    = (const float*)d_in[8];
  const float* wyf    = (const float*)d_in[9];
  float* out = (float*)d_out;

  uint16_t* Cpart = (uint16_t*)d_ws;                               // 33,554,432 B
  float*    wfT   = (float*)((char*)d_ws + (size_t)33554432);      //    262,144 B

  wft_kernel<<<256, 256, 0, stream>>>(wxf, wyf, wfT);
  fused_gemm<<<dim3(128, 8), 256, 0, stream>>>(x, y, wx0, wy0, Cpart);
  finish_kernel<<<1024, 256, 0, stream>>>(x, y, wx_mlp, bx_mlp, wy_mlp, by_mlp,
                                          wfT, Cpart, out);
}